// Round 3
// baseline (6006.083 us; speedup 1.0000x reference)
//
#include <hip/hip_runtime.h>

constexpr int NTOK = 16 * 4096;   // 65536 tokens
constexpr int KSEL = 256;         // top-k = 2*CDIM

// ---------------------------------------------------------------------------
// Tiled fp32 GEMM: C[N,M] = act(A[N,K] @ W[K,M] + bias), act = relu if do_relu
// k accumulated strictly sequentially with fmaf per C element -> matches the
// OpenBLAS sgemm GEBP rounding (one accumulator per element, increasing k).
// ---------------------------------------------------------------------------
template<int K>
__global__ __launch_bounds__(256)
void gemm_f32(const float* __restrict__ A, const float* __restrict__ W,
              const float* __restrict__ bias, float* __restrict__ C,
              int M, int do_relu)
{
    __shared__ float sA[16][68];   // sA[k][row]
    __shared__ float sW[16][68];   // sW[k][col]

    const int tid = threadIdx.x;
    const int tx = tid & 15, ty = tid >> 4;
    const int rowBase = blockIdx.y * 64;
    const int colBase = blockIdx.x * 64;

    const int lr = tid >> 2;
    const int lc = (tid & 3) * 4;
    const int wk = tid >> 4;
    const int wc = (tid & 15) * 4;

    float acc[4][4] = {};

    for (int k0 = 0; k0 < K; k0 += 16) {
        float4 av = *(const float4*)&A[(size_t)(rowBase + lr) * K + k0 + lc];
        float4 wv = *(const float4*)&W[(size_t)(k0 + wk) * M + colBase + wc];
        __syncthreads();
        sA[lc + 0][lr] = av.x;
        sA[lc + 1][lr] = av.y;
        sA[lc + 2][lr] = av.z;
        sA[lc + 3][lr] = av.w;
        *(float4*)&sW[wk][wc] = wv;
        __syncthreads();
#pragma unroll
        for (int k = 0; k < 16; ++k) {
            float4 a4 = *(const float4*)&sA[k][ty * 4];
            float4 w4 = *(const float4*)&sW[k][tx * 4];
            float aa[4] = {a4.x, a4.y, a4.z, a4.w};
            float ww[4] = {w4.x, w4.y, w4.z, w4.w};
#pragma unroll
            for (int a = 0; a < 4; ++a)
#pragma unroll
                for (int b = 0; b < 4; ++b)
                    acc[a][b] = fmaf(aa[a], ww[b], acc[a][b]);
        }
    }

    float4 bv = *(const float4*)&bias[colBase + tx * 4];
#pragma unroll
    for (int a = 0; a < 4; ++a) {
        float4 o;
        o.x = acc[a][0] + bv.x;
        o.y = acc[a][1] + bv.y;
        o.z = acc[a][2] + bv.z;
        o.w = acc[a][3] + bv.w;
        if (do_relu) {
            o.x = fmaxf(o.x, 0.f);
            o.y = fmaxf(o.y, 0.f);
            o.z = fmaxf(o.z, 0.f);
            o.w = fmaxf(o.w, 0.f);
        }
        *(float4*)&C[(size_t)(rowBase + ty * 4 + a) * M + colBase + tx * 4] = o;
    }
}

// ---------------------------------------------------------------------------
// Exact-k top-k mask kernel. One block (256 threads) per token.
// 1) zero h where mask_prev > 0; e = h*h (fp32, matches reference rounding)
// 2) radix-select tau = 256th-largest e (on fp32 bit pattern; e>=0 monotone)
// 3) keep all e > tau; among e == tau keep only the (256 - count_gt)
//    LOWEST-INDEX elements (jax.lax.top_k tie rule) -> exactly 256 kept.
// ---------------------------------------------------------------------------
__global__ __launch_bounds__(256)
void topk_kernel(float* __restrict__ h, const float* __restrict__ mprev)
{
    const int t = blockIdx.x;
    const int tid = threadIdx.x;

    __shared__ unsigned hist[256];
    __shared__ unsigned s_prefix;
    __shared__ int s_need;
    __shared__ unsigned scan[256];

    // thread tid owns contiguous indices 4*tid .. 4*tid+3 (index order = tid order)
    float4 hv = ((const float4*)(h + (size_t)t * 1024))[tid];
    float4 mv = ((const float4*)(mprev + (size_t)t * 1024))[tid];

    float v[4];
    v[0] = mv.x > 0.f ? 0.f : hv.x;
    v[1] = mv.y > 0.f ? 0.f : hv.y;
    v[2] = mv.z > 0.f ? 0.f : hv.z;
    v[3] = mv.w > 0.f ? 0.f : hv.w;

    unsigned u[4];
#pragma unroll
    for (int j = 0; j < 4; ++j)
        u[j] = __float_as_uint(v[j] * v[j]);

    if (tid == 0) { s_prefix = 0u; s_need = KSEL; }

    for (int p = 3; p >= 0; --p) {
        hist[tid] = 0u;
        __syncthreads();
        unsigned pref = s_prefix;
#pragma unroll
        for (int j = 0; j < 4; ++j) {
            bool match = (p == 3) ? true
                       : ((u[j] >> (8 * (p + 1))) == (pref >> (8 * (p + 1))));
            if (match) atomicAdd(&hist[(u[j] >> (8 * p)) & 255u], 1u);
        }
        __syncthreads();
        if (tid == 0) {
            int need = s_need, cum = 0, b = 255;
            for (; b > 0; --b) {
                int c = (int)hist[b];
                if (cum + c >= need) break;
                cum += c;
            }
            s_prefix = s_prefix | ((unsigned)b << (8 * p));
            s_need = need - cum;
        }
        __syncthreads();
    }
    const unsigned tau = s_prefix;

    // exact-k: packed counts (gt in high 16 bits, eq in low 16 bits)
    unsigned cnt_gt = 0, cnt_eq = 0;
#pragma unroll
    for (int j = 0; j < 4; ++j) {
        cnt_gt += (u[j] > tau) ? 1u : 0u;
        cnt_eq += (u[j] == tau) ? 1u : 0u;
    }
    unsigned packed = (cnt_gt << 16) | cnt_eq;
    scan[tid] = packed;
    __syncthreads();
    // Hillis-Steele inclusive scan over 256 threads
    for (int off = 1; off < 256; off <<= 1) {
        unsigned add = (tid >= off) ? scan[tid - off] : 0u;
        __syncthreads();
        scan[tid] += add;
        __syncthreads();
    }
    unsigned inc = scan[tid];
    unsigned total = scan[255];
    int total_gt = (int)(total >> 16);
    int need_eq = KSEL - total_gt;          // 0 <= need_eq (tau is 256th largest)
    int eq_base = (int)((inc - packed) & 0xffffu);  // exclusive eq-prefix

    float o[4];
    int r = 0;
#pragma unroll
    for (int j = 0; j < 4; ++j) {
        bool keep;
        if (u[j] > tau) keep = true;
        else if (u[j] == tau) { keep = (eq_base + r) < need_eq; ++r; }
        else keep = false;
        o[j] = keep ? v[j] : 0.f;
    }
    float4 ov = {o[0], o[1], o[2], o[3]};
    ((float4*)(h + (size_t)t * 1024))[tid] = ov;
}

// ---------------------------------------------------------------------------
extern "C" void kernel_launch(void* const* d_in, const int* in_sizes, int n_in,
                              void* d_out, int out_size, void* d_ws, size_t ws_size,
                              hipStream_t stream)
{
    (void)n_in; (void)out_size; (void)ws_size;

    const float* x  = (const float*)d_in[0];
    const float* mp = (const float*)d_in[1];

    const float *ew[4], *eb[4], *dw[4], *db[4];
    bool interleaved = (in_sizes[4] == 1024 * 512);
    for (int i = 0; i < 4; ++i) {
        if (interleaved) {
            ew[i] = (const float*)d_in[2 + 4 * i];
            eb[i] = (const float*)d_in[3 + 4 * i];
            dw[i] = (const float*)d_in[4 + 4 * i];
            db[i] = (const float*)d_in[5 + 4 * i];
        } else {
            ew[i] = (const float*)d_in[2 + 2 * i];
            eb[i] = (const float*)d_in[3 + 2 * i];
            dw[i] = (const float*)d_in[10 + 2 * i];
            db[i] = (const float*)d_in[11 + 2 * i];
        }
    }

    float* out  = (float*)d_out;                    // ping buffer + final out
    float* bufH = (float*)d_ws;                     // 65536 x 1024
    float* bufP = bufH + (size_t)NTOK * 1024;       // 65536 x 512

    dim3 blk(256);
    auto grid = [](int M) { return dim3(M / 64, NTOK / 64); };

    // encoder
    gemm_f32<512> <<<grid(512),  blk, 0, stream>>>(x,    ew[0], eb[0], out,  512,  1);
    gemm_f32<512> <<<grid(512),  blk, 0, stream>>>(out,  ew[1], eb[1], bufP, 512,  1);
    gemm_f32<512> <<<grid(512),  blk, 0, stream>>>(bufP, ew[2], eb[2], out,  512,  1);
    gemm_f32<512> <<<grid(1024), blk, 0, stream>>>(out,  ew[3], eb[3], bufH, 1024, 0);

    // sparsify (exact k=256, lower-index tie-break)
    topk_kernel<<<dim3(NTOK), blk, 0, stream>>>(bufH, mp);

    // decoder
    gemm_f32<1024><<<grid(512),  blk, 0, stream>>>(bufH, dw[0], db[0], bufP, 512, 1);
    gemm_f32<512> <<<grid(512),  blk, 0, stream>>>(bufP, dw[1], db[1], out,  512, 1);
    gemm_f32<512> <<<grid(512),  blk, 0, stream>>>(out,  dw[2], db[2], bufP, 512, 1);
    gemm_f32<512> <<<grid(512),  blk, 0, stream>>>(bufP, dw[3], db[3], out,  512, 0);
}

// Round 4
// 3348.221 us; speedup vs baseline: 1.7938x; 1.7938x over previous
//
#include <hip/hip_runtime.h>

constexpr int NTOK = 16 * 4096;   // 65536 tokens
constexpr int KSEL = 256;         // top-k = 2*CDIM

using short8 = __attribute__((ext_vector_type(8))) short;
using f32x4  = __attribute__((ext_vector_type(4))) float;

__device__ inline unsigned short bf16_rne(float x) {
    unsigned u = __float_as_uint(x);
    unsigned r = u + 0x7fffu + ((u >> 16) & 1u);
    return (unsigned short)(r >> 16);
}
__device__ inline float bf16_f32(unsigned short h) {
    return __uint_as_float((unsigned)h << 16);
}

// ---------------------------------------------------------------------------
// fp32 GEMM (encoder): C = act(A@W + b), optional fused mask-zeroing.
// 128x64 tile, 256 threads, 8x4 per thread. Each C element is a single
// sequential-k fmaf chain (k ascending) -> bit-identical to the R3 kernel.
// ---------------------------------------------------------------------------
template<int K>
__global__ __launch_bounds__(256)
void gemm_f32(const float* __restrict__ A, const float* __restrict__ W,
              const float* __restrict__ bias, float* __restrict__ C,
              int M, int do_relu, const float* __restrict__ mask)
{
    __shared__ float sA[16][136];   // [k][row], 128 rows + pad
    __shared__ float sW[16][68];    // [k][col]

    const int tid = threadIdx.x;
    const int tx = tid & 15, ty = tid >> 4;
    const int rowBase = blockIdx.y * 128;
    const int colBase = blockIdx.x * 64;

    const int lr = tid >> 1;          // A row 0..127
    const int lk = (tid & 1) * 8;     // A k offset 0/8
    const int wk = tid >> 4;          // W k row 0..15
    const int wc = (tid & 15) * 4;    // W col offset

    float acc[8][4] = {};

    for (int k0 = 0; k0 < K; k0 += 16) {
        const float* ap = &A[(size_t)(rowBase + lr) * K + k0 + lk];
        float4 a0 = *(const float4*)ap;
        float4 a1 = *(const float4*)(ap + 4);
        float4 wv = *(const float4*)&W[(size_t)(k0 + wk) * M + colBase + wc];
        __syncthreads();
        sA[lk + 0][lr] = a0.x; sA[lk + 1][lr] = a0.y;
        sA[lk + 2][lr] = a0.z; sA[lk + 3][lr] = a0.w;
        sA[lk + 4][lr] = a1.x; sA[lk + 5][lr] = a1.y;
        sA[lk + 6][lr] = a1.z; sA[lk + 7][lr] = a1.w;
        *(float4*)&sW[wk][wc] = wv;
        __syncthreads();
#pragma unroll
        for (int k = 0; k < 16; ++k) {
            float4 aA = *(const float4*)&sA[k][ty * 8];
            float4 aB = *(const float4*)&sA[k][ty * 8 + 4];
            float4 w4 = *(const float4*)&sW[k][tx * 4];
            float av[8] = {aA.x, aA.y, aA.z, aA.w, aB.x, aB.y, aB.z, aB.w};
            float wl[4] = {w4.x, w4.y, w4.z, w4.w};
#pragma unroll
            for (int a = 0; a < 8; ++a)
#pragma unroll
                for (int b = 0; b < 4; ++b)
                    acc[a][b] = fmaf(av[a], wl[b], acc[a][b]);
        }
    }

    float4 bv = *(const float4*)&bias[colBase + tx * 4];
    float bb[4] = {bv.x, bv.y, bv.z, bv.w};
#pragma unroll
    for (int a = 0; a < 8; ++a) {
        int row = rowBase + ty * 8 + a;
        float o[4];
#pragma unroll
        for (int b = 0; b < 4; ++b) {
            o[b] = acc[a][b] + bb[b];
            if (do_relu) o[b] = fmaxf(o[b], 0.f);
        }
        if (mask) {
            float4 mv = *(const float4*)&mask[(size_t)row * M + colBase + tx * 4];
            float mm[4] = {mv.x, mv.y, mv.z, mv.w};
#pragma unroll
            for (int b = 0; b < 4; ++b) if (mm[b] > 0.f) o[b] = 0.f;
        }
        float4 ov = {o[0], o[1], o[2], o[3]};
        *(float4*)&C[(size_t)row * M + colBase + tx * 4] = ov;
    }
}

// ---------------------------------------------------------------------------
// Weight split+transpose: W[K][M] fp32 -> WhT/WlT [M][K] bf16 (hi + lo).
// ---------------------------------------------------------------------------
__global__ __launch_bounds__(256)
void wsplit_t(const float* __restrict__ W, unsigned short* __restrict__ WhT,
              unsigned short* __restrict__ WlT, int K, int M)
{
    __shared__ float tile[32][33];
    const int tid = threadIdx.x;
    const int tx = tid & 31, ty = tid >> 5;          // ty 0..7
    const int m0 = blockIdx.x * 32, k0 = blockIdx.y * 32;
#pragma unroll
    for (int i = 0; i < 4; ++i)
        tile[ty + 8 * i][tx] = W[(size_t)(k0 + ty + 8 * i) * M + m0 + tx];
    __syncthreads();
#pragma unroll
    for (int i = 0; i < 4; ++i) {
        int m = ty + 8 * i;
        float v = tile[tx][m];
        unsigned short hh = bf16_rne(v);
        unsigned short ll = bf16_rne(v - bf16_f32(hh));
        WhT[(size_t)(m0 + m) * K + k0 + tx] = hh;
        WlT[(size_t)(m0 + m) * K + k0 + tx] = ll;
    }
}

// ---------------------------------------------------------------------------
// Split-bf16 MFMA GEMM (decoder): C = act(A@W + b) with A fp32 split on the
// fly, W pre-split/transposed. 128x128 tile, 4 waves, 4x4 16x16x32 mfma
// tiles per wave, 3 products (hh + lh + hl) per tile -> ~2^-16 rel accuracy.
// ---------------------------------------------------------------------------
template<int K>
__global__ __launch_bounds__(256)
void gemm_mfma(const float* __restrict__ A, const unsigned short* __restrict__ WhT,
               const unsigned short* __restrict__ WlT, const float* __restrict__ bias,
               float* __restrict__ C, int M, int do_relu)
{
    __shared__ __align__(16) unsigned short sAh[128 * 40];
    __shared__ __align__(16) unsigned short sAl[128 * 40];
    __shared__ __align__(16) unsigned short sBh[128 * 40];
    __shared__ __align__(16) unsigned short sBl[128 * 40];

    const int tid = threadIdx.x;
    const int lane = tid & 63, wid = tid >> 6;
    const int quad = lane >> 4, l16 = lane & 15;
    const int rowBase = blockIdx.y * 128, colBase = blockIdx.x * 128;
    const int wr = (wid & 1) * 64, wc = (wid >> 1) * 64;

    const int sr = tid >> 1;          // staging row/col 0..127
    const int sk = (tid & 1) * 16;    // staging k offset 0/16

    f32x4 acc[4][4];
#pragma unroll
    for (int i = 0; i < 4; ++i)
#pragma unroll
        for (int j = 0; j < 4; ++j)
            acc[i][j] = (f32x4){0.f, 0.f, 0.f, 0.f};

    for (int k0 = 0; k0 < K; k0 += 32) {
        const float* ap = &A[(size_t)(rowBase + sr) * K + k0 + sk];
        float4 a0 = *(const float4*)ap;
        float4 a1 = *(const float4*)(ap + 4);
        float4 a2 = *(const float4*)(ap + 8);
        float4 a3 = *(const float4*)(ap + 12);
        const unsigned short* whp = &WhT[(size_t)(colBase + sr) * K + k0 + sk];
        const unsigned short* wlp = &WlT[(size_t)(colBase + sr) * K + k0 + sk];
        short8 wh0 = *(const short8*)whp;
        short8 wh1 = *(const short8*)(whp + 8);
        short8 wl0 = *(const short8*)wlp;
        short8 wl1 = *(const short8*)(wlp + 8);

        float f[16] = {a0.x, a0.y, a0.z, a0.w, a1.x, a1.y, a1.z, a1.w,
                       a2.x, a2.y, a2.z, a2.w, a3.x, a3.y, a3.z, a3.w};
        unsigned short __align__(16) hs[16], ls[16];
#pragma unroll
        for (int j = 0; j < 16; ++j) {
            hs[j] = bf16_rne(f[j]);
            ls[j] = bf16_rne(f[j] - bf16_f32(hs[j]));
        }

        __syncthreads();
        *(short8*)&sAh[sr * 40 + sk]     = *(short8*)&hs[0];
        *(short8*)&sAh[sr * 40 + sk + 8] = *(short8*)&hs[8];
        *(short8*)&sAl[sr * 40 + sk]     = *(short8*)&ls[0];
        *(short8*)&sAl[sr * 40 + sk + 8] = *(short8*)&ls[8];
        *(short8*)&sBh[sr * 40 + sk]     = wh0;
        *(short8*)&sBh[sr * 40 + sk + 8] = wh1;
        *(short8*)&sBl[sr * 40 + sk]     = wl0;
        *(short8*)&sBl[sr * 40 + sk + 8] = wl1;
        __syncthreads();

        short8 ah[4], al[4], bh[4], bl[4];
#pragma unroll
        for (int t4 = 0; t4 < 4; ++t4) {
            ah[t4] = *(const short8*)&sAh[(wr + t4 * 16 + l16) * 40 + quad * 8];
            al[t4] = *(const short8*)&sAl[(wr + t4 * 16 + l16) * 40 + quad * 8];
            bh[t4] = *(const short8*)&sBh[(wc + t4 * 16 + l16) * 40 + quad * 8];
            bl[t4] = *(const short8*)&sBl[(wc + t4 * 16 + l16) * 40 + quad * 8];
        }
#pragma unroll
        for (int rt = 0; rt < 4; ++rt)
#pragma unroll
            for (int ct = 0; ct < 4; ++ct) {
                acc[rt][ct] = __builtin_amdgcn_mfma_f32_16x16x32_bf16(ah[rt], bh[ct], acc[rt][ct], 0, 0, 0);
                acc[rt][ct] = __builtin_amdgcn_mfma_f32_16x16x32_bf16(al[rt], bh[ct], acc[rt][ct], 0, 0, 0);
                acc[rt][ct] = __builtin_amdgcn_mfma_f32_16x16x32_bf16(ah[rt], bl[ct], acc[rt][ct], 0, 0, 0);
            }
    }

#pragma unroll
    for (int ct = 0; ct < 4; ++ct) {
        int col = colBase + wc + ct * 16 + l16;
        float bc = bias[col];
#pragma unroll
        for (int rt = 0; rt < 4; ++rt)
#pragma unroll
            for (int r = 0; r < 4; ++r) {
                int row = rowBase + wr + rt * 16 + quad * 4 + r;
                float v = acc[rt][ct][r] + bc;
                if (do_relu) v = fmaxf(v, 0.f);
                C[(size_t)row * M + col] = v;
            }
    }
}

// ---------------------------------------------------------------------------
// Exact-k topk (input pre-masked by encoder L4 epilogue). Radix select on
// fp32 energy bit patterns with wave-shfl suffix scans (no serial loops);
// keep e > tau plus lowest-index among e == tau -> exactly 256 kept.
// ---------------------------------------------------------------------------
__global__ __launch_bounds__(256)
void topk_kernel(float* __restrict__ h)
{
    const int t = blockIdx.x, tid = threadIdx.x;
    const int lane = tid & 63, wid = tid >> 6;

    __shared__ unsigned hist[256];
    __shared__ unsigned wsum[4];
    __shared__ unsigned s_prefix;
    __shared__ int s_need;

    float4 hv = ((const float4*)(h + (size_t)t * 1024))[tid];
    float v[4] = {hv.x, hv.y, hv.z, hv.w};
    unsigned u[4];
#pragma unroll
    for (int j = 0; j < 4; ++j) u[j] = __float_as_uint(v[j] * v[j]);

    if (tid == 0) { s_prefix = 0u; s_need = KSEL; }
    __syncthreads();

    for (int p = 3; p >= 0; --p) {
        unsigned pref = s_prefix;       // stable: trailing barrier of prev pass
        int need = s_need;
        hist[tid] = 0u;
        __syncthreads();
#pragma unroll
        for (int j = 0; j < 4; ++j) {
            bool match = (p == 3) || ((u[j] >> (8 * (p + 1))) == (pref >> (8 * (p + 1))));
            if (match) atomicAdd(&hist[(u[j] >> (8 * p)) & 255u], 1u);
        }
        __syncthreads();
        unsigned x = hist[tid];
        unsigned s = x;                 // inclusive suffix within wave
#pragma unroll
        for (int off = 1; off < 64; off <<= 1) {
            unsigned o = __shfl_down(s, off);
            if (lane + off < 64) s += o;
        }
        if (lane == 0) wsum[wid] = s;
        __syncthreads();
        unsigned above = 0;
        for (int w = wid + 1; w < 4; ++w) above += wsum[w];
        unsigned incl = s + above;
        unsigned excl = incl - x;
        if (incl >= (unsigned)need && excl < (unsigned)need) {
            s_prefix = pref | ((unsigned)tid << (8 * p));
            s_need = need - (int)excl;
        }
        __syncthreads();
    }
    const unsigned tau = s_prefix;

    unsigned cg = 0, ce = 0;
#pragma unroll
    for (int j = 0; j < 4; ++j) {
        cg += (u[j] > tau) ? 1u : 0u;
        ce += (u[j] == tau) ? 1u : 0u;
    }
    unsigned packed = (cg << 16) | ce;
    unsigned ps = packed;               // inclusive prefix within wave
#pragma unroll
    for (int off = 1; off < 64; off <<= 1) {
        unsigned o = __shfl_up(ps, off);
        if (lane >= off) ps += o;
    }
    if (lane == 63) wsum[wid] = ps;
    __syncthreads();
    unsigned below = 0;
    for (int w = 0; w < wid; ++w) below += wsum[w];
    unsigned total = wsum[0] + wsum[1] + wsum[2] + wsum[3];
    unsigned incl = ps + below;
    int need_eq = KSEL - (int)(total >> 16);
    int eq_base = (int)((incl - packed) & 0xffffu);

    float o[4]; int r = 0;
#pragma unroll
    for (int j = 0; j < 4; ++j) {
        bool keep;
        if (u[j] > tau) keep = true;
        else if (u[j] == tau) { keep = (eq_base + r) < need_eq; ++r; }
        else keep = false;
        o[j] = keep ? v[j] : 0.f;
    }
    float4 ov = {o[0], o[1], o[2], o[3]};
    ((float4*)(h + (size_t)t * 1024))[tid] = ov;
}

// ---------------------------------------------------------------------------
extern "C" void kernel_launch(void* const* d_in, const int* in_sizes, int n_in,
                              void* d_out, int out_size, void* d_ws, size_t ws_size,
                              hipStream_t stream)
{
    (void)n_in; (void)out_size; (void)ws_size;

    const float* x  = (const float*)d_in[0];
    const float* mp = (const float*)d_in[1];

    const float *ew[4], *eb[4], *dw[4], *db[4];
    bool interleaved = (in_sizes[4] == 1024 * 512);
    for (int i = 0; i < 4; ++i) {
        if (interleaved) {
            ew[i] = (const float*)d_in[2 + 4 * i];
            eb[i] = (const float*)d_in[3 + 4 * i];
            dw[i] = (const float*)d_in[4 + 4 * i];
            db[i] = (const float*)d_in[5 + 4 * i];
        } else {
            ew[i] = (const float*)d_in[2 + 2 * i];
            eb[i] = (const float*)d_in[3 + 2 * i];
            dw[i] = (const float*)d_in[10 + 2 * i];
            db[i] = (const float*)d_in[11 + 2 * i];
        }
    }

    float* out  = (float*)d_out;
    float* bufH = (float*)d_ws;                     // [NTOK][1024] f32, 256 MiB
    float* bufP = bufH + (size_t)NTOK * 1024;       // [NTOK][512]  f32, 128 MiB

    // Split decoder weights live in dead buffer windows (no ws growth):
    //  - W0..W2 (4 MiB) in d_out: free until dec2 (and fully rewritten by dec4)
    //  - W3 (1 MiB) in bufH tail @192 MiB: free once dec1 has consumed h
    unsigned short* Wh0 = (unsigned short*)d_out;
    unsigned short* Wl0 = Wh0 + 1024 * 512;
    unsigned short* Wh1 = Wl0 + 1024 * 512;
    unsigned short* Wl1 = Wh1 + 512 * 512;
    unsigned short* Wh2 = Wl1 + 512 * 512;
    unsigned short* Wl2 = Wh2 + 512 * 512;
    unsigned short* Wh3 = (unsigned short*)((char*)d_ws + (size_t)192 * 1024 * 1024);
    unsigned short* Wl3 = Wh3 + 512 * 512;

    dim3 blk(256);

    // decoder weight split+transpose (W0-W2 -> d_out region; encoder never touches d_out)
    wsplit_t<<<dim3(512 / 32, 1024 / 32), blk, 0, stream>>>(dw[0], Wh0, Wl0, 1024, 512);
    wsplit_t<<<dim3(512 / 32, 512 / 32),  blk, 0, stream>>>(dw[1], Wh1, Wl1, 512, 512);
    wsplit_t<<<dim3(512 / 32, 512 / 32),  blk, 0, stream>>>(dw[2], Wh2, Wl2, 512, 512);

    // encoder: pings bufP <-> bufH-front; L4 fuses mask-zeroing
    dim3 ge(512 / 64, NTOK / 128);
    dim3 ge4(1024 / 64, NTOK / 128);
    gemm_f32<512><<<ge,  blk, 0, stream>>>(x,    ew[0], eb[0], bufP, 512,  1, nullptr);
    gemm_f32<512><<<ge,  blk, 0, stream>>>(bufP, ew[1], eb[1], bufH, 512,  1, nullptr);
    gemm_f32<512><<<ge,  blk, 0, stream>>>(bufH, ew[2], eb[2], bufP, 512,  1, nullptr);
    gemm_f32<512><<<ge4, blk, 0, stream>>>(bufP, ew[3], eb[3], bufH, 1024, 0, mp);

    // exact-k sparsify (in place on bufH)
    topk_kernel<<<dim3(NTOK), blk, 0, stream>>>(bufH);

    // decoder (split-bf16 MFMA): bufH -> bufP -> bufH-front -> bufP -> out
    dim3 gd(512 / 128, NTOK / 128);
    gemm_mfma<1024><<<gd, blk, 0, stream>>>(bufH, Wh0, Wl0, db[0], bufP, 512, 1);
    wsplit_t<<<dim3(512 / 32, 512 / 32), blk, 0, stream>>>(dw[3], Wh3, Wl3, 512, 512);
    gemm_mfma<512> <<<gd, blk, 0, stream>>>(bufP, Wh1, Wl1, db[1], bufH, 512, 1);
    gemm_mfma<512> <<<gd, blk, 0, stream>>>(bufH, Wh2, Wl2, db[2], bufP, 512, 1);
    gemm_mfma<512> <<<gd, blk, 0, stream>>>(bufP, Wh3, Wl3, db[3], out,  512, 0);
}